// Round 1
// baseline (367.857 us; speedup 1.0000x reference)
//
#include <hip/hip_runtime.h>
#include <hip/hip_bf16.h>
#include <cstdint>

#define B_    256
#define S_    49
#define D_    448
#define H_    8
#define KD_   32
#define ED_   128
#define NTOK  (B_*S_)          // 12544 = 98*128
#define QKVO  1536
#define MLPH  1792
#define SCALE_ 0.17677669529663687f   // 32^-0.5

using bf16x8 = __attribute__((ext_vector_type(8))) __bf16;
using f32x4  = __attribute__((ext_vector_type(4))) float;

__device__ __forceinline__ unsigned short f2bf(float f){
  uint32_t u = __builtin_bit_cast(uint32_t, f);
  u += 0x7fffu + ((u >> 16) & 1u);     // RNE
  return (unsigned short)(u >> 16);
}
__device__ __forceinline__ float b2f(unsigned short b){
  uint32_t u = ((uint32_t)b) << 16;
  return __builtin_bit_cast(float, u);
}

__device__ __forceinline__ void gload_lds16(const void* g, void* l){
  __builtin_amdgcn_global_load_lds(
      (const __attribute__((address_space(1))) void*)g,
      (__attribute__((address_space(3))) void*)l, 16, 0, 0);
}

// ---------------- weight fp32 -> bf16 (with zero row padding) ----------------
__global__ __launch_bounds__(256)
void cvt_k(const float* __restrict__ src, unsigned short* __restrict__ dst,
           int Nout, int K, long total){
  long i = (long)blockIdx.x * 256 + threadIdx.x;
  if (i >= total) return;
  long row = i / K;
  unsigned short v = 0;
  if (row < Nout) v = f2bf(src[i]);
  dst[i] = v;
}

// ---------------- LayerNorm over D=448, one block (7 waves) per token --------
__global__ __launch_bounds__(448)
void ln_k(const float* __restrict__ x, const float* __restrict__ w,
          const float* __restrict__ b, unsigned short* __restrict__ out){
  const int tok = blockIdx.x, t = threadIdx.x;
  const float v = x[(size_t)tok*448 + t];
  float s1 = v, s2 = v*v;
  #pragma unroll
  for (int o = 32; o; o >>= 1){ s1 += __shfl_xor(s1, o); s2 += __shfl_xor(s2, o); }
  __shared__ float a1[7], a2[7];
  const int wid = t >> 6;
  if ((t & 63) == 0){ a1[wid] = s1; a2[wid] = s2; }
  __syncthreads();
  float S1 = 0.f, S2 = 0.f;
  #pragma unroll
  for (int i = 0; i < 7; ++i){ S1 += a1[i]; S2 += a2[i]; }
  const float mu  = S1 * (1.f/448.f);
  const float var = S2 * (1.f/448.f) - mu*mu;
  const float rs  = rsqrtf(var + 1e-12f);
  out[(size_t)tok*448 + t] = f2bf((v - mu)*rs*w[t] + b[t]);
}

// ---------------- bf16 MFMA GEMM: C[M,Nout] = A[M,K] @ W[Nout,K]^T -----------
// m97 structure: 128x128 tile, BK=64, 4 waves (2x2 of 64x64), global_load_lds w=16.
// EPI: 0 = +bias -> bf16 out; 1 = out = resid + scale*(v+bias) (f32);
//      2 = gelu(v+bias) -> bf16; 3 = out += scale*(v+bias) (f32 RMW)
template<int EPI>
__global__ __launch_bounds__(256)
void gemm_k(const unsigned short* __restrict__ A,
            const unsigned short* __restrict__ W,
            int K, int Nout,
            const float* __restrict__ bias,
            const float* __restrict__ resid,
            const float* __restrict__ scale,
            float* __restrict__ outF,
            unsigned short* __restrict__ outB,
            int ldo)
{
  __shared__ unsigned short As[128*64];
  __shared__ unsigned short Bs[128*64];
  const int t = threadIdx.x;
  const int lane = t & 63, wid = t >> 6;
  const int wm = wid >> 1, wn = wid & 1;
  f32x4 acc[4][4] = {};

  const size_t aBase = (size_t)blockIdx.x * 128 * K;
  const size_t bBase = (size_t)blockIdx.y * 128 * K;
  const int srow = lane >> 3;          // 8 lanes per 64-elem row
  const int scol = (lane & 7) * 8;
  const int nkt = K >> 6;

  for (int kt = 0; kt < nkt; ++kt){
    const int k0 = kt * 64;
    #pragma unroll
    for (int i = 0; i < 4; ++i){
      const int c = wid*4 + i;
      const int row = c*8 + srow;
      gload_lds16(A + aBase + (size_t)row*K + (k0 + scol), &As[c*512]);
    }
    #pragma unroll
    for (int i = 0; i < 4; ++i){
      const int c = wid*4 + i;
      const int row = c*8 + srow;
      gload_lds16(W + bBase + (size_t)row*K + (k0 + scol), &Bs[c*512]);
    }
    __syncthreads();   // drains vmcnt before barrier (compiler-inserted)
    #pragma unroll
    for (int ks = 0; ks < 2; ++ks){
      const int kk = ks*32 + (lane >> 4)*8;
      bf16x8 af[4], bfr[4];
      #pragma unroll
      for (int mf = 0; mf < 4; ++mf)
        af[mf]  = *reinterpret_cast<const bf16x8*>(&As[(wm*64 + mf*16 + (lane & 15))*64 + kk]);
      #pragma unroll
      for (int nf = 0; nf < 4; ++nf)
        bfr[nf] = *reinterpret_cast<const bf16x8*>(&Bs[(wn*64 + nf*16 + (lane & 15))*64 + kk]);
      #pragma unroll
      for (int mf = 0; mf < 4; ++mf)
        #pragma unroll
        for (int nf = 0; nf < 4; ++nf)
          acc[mf][nf] = __builtin_amdgcn_mfma_f32_16x16x32_bf16(af[mf], bfr[nf], acc[mf][nf], 0, 0, 0);
    }
    __syncthreads();
  }

  // C/D layout: col = lane&15, row = (lane>>4)*4 + j  [m89/m91-verified]
  const int rbase = blockIdx.x*128 + wm*64 + (lane >> 4)*4;
  const int cbase = blockIdx.y*128 + wn*64 + (lane & 15);
  #pragma unroll
  for (int mf = 0; mf < 4; ++mf){
    #pragma unroll
    for (int nf = 0; nf < 4; ++nf){
      const int col = cbase + nf*16;
      if (col < Nout){
        const float bi = bias[col];
        #pragma unroll
        for (int j = 0; j < 4; ++j){
          const int row = rbase + mf*16 + j;
          const float v = acc[mf][nf][j] + bi;
          if (EPI == 0){
            outB[(size_t)row*ldo + col] = f2bf(v);
          } else if (EPI == 1){
            const size_t o = (size_t)row*ldo + col;
            outF[o] = resid[o] + scale[col]*v;
          } else if (EPI == 2){
            const float g = 0.5f*v*(1.0f + erff(v*0.70710678118654752f));
            outB[(size_t)row*ldo + col] = f2bf(g);
          } else {
            const size_t o = (size_t)row*ldo + col;
            outF[o] += scale[col]*v;
          }
        }
      }
    }
  }
}

// ---------------- attention: one block per (b,h), 49x49 scores --------------
__global__ __launch_bounds__(256)
void attn_k(const unsigned short* __restrict__ qkv,
            const float* __restrict__ biases,
            const int* __restrict__ idxs,
            unsigned short* __restrict__ ctx)
{
  const int bh = blockIdx.x;
  const int b = bh >> 3, h = bh & 7;
  __shared__ float Qs[49][33];   // +1 pad: scores loop reads rows per lane
  __shared__ float Ks[49][33];
  __shared__ float Vs[49][128];
  __shared__ float Ps[49][52];
  __shared__ float bh_[49];
  const int t = threadIdx.x;

  const size_t base = ((size_t)b*49)*QKVO + h*192;
  for (int e = t; e < 49*192; e += 256){
    const int s = e / 192, c = e % 192;
    const float v = b2f(qkv[base + (size_t)s*QKVO + c]);
    if (c < 32)       Qs[s][c]      = v * SCALE_;
    else if (c < 64)  Ks[s][c-32]   = v;
    else              Vs[s][c-64]   = v;
  }
  if (t < 49) bh_[t] = biases[h*49 + t];
  __syncthreads();

  for (int e = t; e < 49*49; e += 256){
    const int q = e / 49, k = e % 49;
    float s = 0.f;
    #pragma unroll
    for (int i = 0; i < 32; ++i) s += Qs[q][i]*Ks[k][i];
    Ps[q][k] = s + bh_[idxs[e]];
  }
  __syncthreads();

  const int wid = t >> 6, lane = t & 63;
  for (int r = wid; r < 49; r += 4){
    float v = (lane < 49) ? Ps[r][lane] : -1e30f;
    float m = v;
    #pragma unroll
    for (int o = 32; o; o >>= 1) m = fmaxf(m, __shfl_xor(m, o));
    float e = (lane < 49) ? __expf(v - m) : 0.f;
    float s = e;
    #pragma unroll
    for (int o = 32; o; o >>= 1) s += __shfl_xor(s, o);
    if (lane < 49) Ps[r][lane] = e / s;
  }
  __syncthreads();

  const size_t obase = ((size_t)b*49)*1024 + h*128;
  for (int e = t; e < 49*128; e += 256){
    const int q = e >> 7, d = e & 127;
    float s = 0.f;
    #pragma unroll
    for (int k = 0; k < 49; ++k) s += Ps[q][k]*Vs[k][d];
    ctx[obase + (size_t)q*1024 + d] = f2bf(s);
  }
}

// ---------------------------------------------------------------------------
extern "C" void kernel_launch(void* const* d_in, const int* in_sizes, int n_in,
                              void* d_out, int out_size, void* d_ws, size_t ws_size,
                              hipStream_t stream)
{
  const float* hidden = (const float*)d_in[0];
  const float* ln2w   = (const float*)d_in[1];
  const float* ln2b   = (const float*)d_in[2];
  const float* qkvw   = (const float*)d_in[3];
  const float* qkvb   = (const float*)d_in[4];
  const float* projw  = (const float*)d_in[5];
  const float* projb  = (const float*)d_in[6];
  const float* attb   = (const float*)d_in[7];
  const float* fc1w   = (const float*)d_in[8];
  const float* fc1b   = (const float*)d_in[9];
  const float* fc2w   = (const float*)d_in[10];
  const float* fc2b   = (const float*)d_in[11];
  const float* ls1    = (const float*)d_in[12];
  const float* ls2    = (const float*)d_in[13];
  const int*   aidx   = (const int*)d_in[14];
  float* out = (float*)d_out;

  char* p = (char*)d_ws;
  auto alloc = [&](size_t bytes){ void* r = (void*)p; p += (bytes + 255) & ~(size_t)255; return r; };
  unsigned short* wqkv  = (unsigned short*)alloc((size_t)QKVO*448*2);
  unsigned short* wproj = (unsigned short*)alloc((size_t)512*1024*2);   // 448 padded to 512
  unsigned short* wfc1  = (unsigned short*)alloc((size_t)MLPH*448*2);
  unsigned short* wfc2  = (unsigned short*)alloc((size_t)512*MLPH*2);   // 448 padded to 512
  unsigned short* normb = (unsigned short*)alloc((size_t)NTOK*448*2);
  unsigned short* qkvv  = (unsigned short*)alloc((size_t)NTOK*QKVO*2);
  unsigned short* ctx   = (unsigned short*)alloc((size_t)NTOK*1024*2);
  unsigned short* hid   = (unsigned short*)alloc((size_t)NTOK*MLPH*2);

  auto cvt = [&](const float* s, unsigned short* d, int Nout, int K, long total){
    cvt_k<<<(int)((total + 255)/256), 256, 0, stream>>>(s, d, Nout, K, total);
  };
  cvt(qkvw,  wqkv,  QKVO, 448,  (long)QKVO*448);
  cvt(projw, wproj, 448,  1024, (long)512*1024);
  cvt(fc1w,  wfc1,  MLPH, 448,  (long)MLPH*448);
  cvt(fc2w,  wfc2,  448,  MLPH, (long)512*MLPH);

  ln_k<<<NTOK, 448, 0, stream>>>(hidden, ln2w, ln2b, normb);

  // QKV: [12544,448] x [1536,448]^T -> bf16 qkv
  gemm_k<0><<<dim3(98,12), 256, 0, stream>>>(normb, wqkv, 448, QKVO, qkvb,
                                             nullptr, nullptr, nullptr, qkvv, QKVO);
  // attention per (b,h)
  attn_k<<<B_*H_, 256, 0, stream>>>(qkvv, attb, aidx, ctx);
  // proj: [12544,1024] x [448,1024]^T -> out = hidden + ls1*(..)
  gemm_k<1><<<dim3(98,4), 256, 0, stream>>>(ctx, wproj, 1024, 448, projb,
                                            hidden, ls1, out, nullptr, 448);
  // FC1: [12544,448] x [1792,448]^T -> gelu -> bf16 hid
  gemm_k<2><<<dim3(98,14), 256, 0, stream>>>(normb, wfc1, 448, MLPH, fc1b,
                                             nullptr, nullptr, nullptr, hid, MLPH);
  // FC2: [12544,1792] x [448,1792]^T -> out += ls2*(..)
  gemm_k<3><<<dim3(98,4), 256, 0, stream>>>(hid, wfc2, MLPH, 448, fc2b,
                                            nullptr, ls2, out, nullptr, 448);
}

// Round 2
// 255.038 us; speedup vs baseline: 1.4424x; 1.4424x over previous
//
#include <hip/hip_runtime.h>
#include <hip/hip_bf16.h>
#include <cstdint>

#define B_    256
#define S_    49
#define D_    448
#define H_    8
#define KD_   32
#define ED_   128
#define NTOK  (B_*S_)          // 12544 = 98*128
#define QKVO  1536
#define MLPH  1792
#define SCALE_ 0.17677669529663687f   // 32^-0.5

using bf16x8  = __attribute__((ext_vector_type(8))) __bf16;
using ushort8 = __attribute__((ext_vector_type(8))) unsigned short;
using f32x4   = __attribute__((ext_vector_type(4))) float;

__device__ __forceinline__ unsigned short f2bf(float f){
  uint32_t u = __builtin_bit_cast(uint32_t, f);
  u += 0x7fffu + ((u >> 16) & 1u);     // RNE
  return (unsigned short)(u >> 16);
}
__device__ __forceinline__ float b2f(unsigned short b){
  uint32_t u = ((uint32_t)b) << 16;
  return __builtin_bit_cast(float, u);
}

__device__ __forceinline__ void gload_lds16(const void* g, void* l){
  __builtin_amdgcn_global_load_lds(
      (const __attribute__((address_space(1))) void*)g,
      (__attribute__((address_space(3))) void*)l, 16, 0, 0);
}

// ---------------- weight fp32 -> bf16 (with zero row padding) ----------------
__global__ __launch_bounds__(256)
void cvt_k(const float* __restrict__ src, unsigned short* __restrict__ dst,
           int Nout, int K, long total){
  long i = (long)blockIdx.x * 256 + threadIdx.x;
  if (i >= total) return;
  long row = i / K;
  unsigned short v = 0;
  if (row < Nout) v = f2bf(src[i]);
  dst[i] = v;
}

// ---------------- attention bias table: biasf[h][64][64] ---------------------
__global__ __launch_bounds__(256)
void biasf_k(const float* __restrict__ attb, const int* __restrict__ idxs,
             float* __restrict__ biasf){
  int i = blockIdx.x * 256 + threadIdx.x;
  if (i >= 8*64*64) return;
  int h = i >> 12, r = (i >> 6) & 63, c = i & 63;
  float v;
  if (c >= 49) v = -1e30f;                       // masked key -> softmax weight 0
  else { int q = r < 49 ? r : 48; v = attb[h*49 + idxs[q*49 + c]]; }
  biasf[i] = v;
}

// ---------------- LayerNorm over D=448, one block (7 waves) per token --------
__global__ __launch_bounds__(448)
void ln_k(const float* __restrict__ x, const float* __restrict__ w,
          const float* __restrict__ b, unsigned short* __restrict__ out){
  const int tok = blockIdx.x, t = threadIdx.x;
  const float v = x[(size_t)tok*448 + t];
  float s1 = v, s2 = v*v;
  #pragma unroll
  for (int o = 32; o; o >>= 1){ s1 += __shfl_xor(s1, o); s2 += __shfl_xor(s2, o); }
  __shared__ float a1[7], a2[7];
  const int wid = t >> 6;
  if ((t & 63) == 0){ a1[wid] = s1; a2[wid] = s2; }
  __syncthreads();
  float S1 = 0.f, S2 = 0.f;
  #pragma unroll
  for (int i = 0; i < 7; ++i){ S1 += a1[i]; S2 += a2[i]; }
  const float mu  = S1 * (1.f/448.f);
  const float var = S2 * (1.f/448.f) - mu*mu;
  const float rs  = rsqrtf(var + 1e-12f);
  out[(size_t)tok*448 + t] = f2bf((v - mu)*rs*w[t] + b[t]);
}

// ---------------- bf16 MFMA GEMM: C[M,Nout] = A[M,K] @ W[Nout,K]^T -----------
template<int EPI>
__global__ __launch_bounds__(256)
void gemm_k(const unsigned short* __restrict__ A,
            const unsigned short* __restrict__ W,
            int K, int Nout,
            const float* __restrict__ bias,
            const float* __restrict__ resid,
            const float* __restrict__ scale,
            float* __restrict__ outF,
            unsigned short* __restrict__ outB,
            int ldo)
{
  __shared__ unsigned short As[128*64];
  __shared__ unsigned short Bs[128*64];
  const int t = threadIdx.x;
  const int lane = t & 63, wid = t >> 6;
  const int wm = wid >> 1, wn = wid & 1;
  f32x4 acc[4][4] = {};

  const size_t aBase = (size_t)blockIdx.x * 128 * K;
  const size_t bBase = (size_t)blockIdx.y * 128 * K;
  const int srow = lane >> 3;          // 8 lanes per 64-elem row
  const int scol = (lane & 7) * 8;
  const int nkt = K >> 6;

  for (int kt = 0; kt < nkt; ++kt){
    const int k0 = kt * 64;
    #pragma unroll
    for (int i = 0; i < 4; ++i){
      const int c = wid*4 + i;
      const int row = c*8 + srow;
      gload_lds16(A + aBase + (size_t)row*K + (k0 + scol), &As[c*512]);
    }
    #pragma unroll
    for (int i = 0; i < 4; ++i){
      const int c = wid*4 + i;
      const int row = c*8 + srow;
      gload_lds16(W + bBase + (size_t)row*K + (k0 + scol), &Bs[c*512]);
    }
    __syncthreads();
    #pragma unroll
    for (int ks = 0; ks < 2; ++ks){
      const int kk = ks*32 + (lane >> 4)*8;
      bf16x8 af[4], bfr[4];
      #pragma unroll
      for (int mf = 0; mf < 4; ++mf)
        af[mf]  = *reinterpret_cast<const bf16x8*>(&As[(wm*64 + mf*16 + (lane & 15))*64 + kk]);
      #pragma unroll
      for (int nf = 0; nf < 4; ++nf)
        bfr[nf] = *reinterpret_cast<const bf16x8*>(&Bs[(wn*64 + nf*16 + (lane & 15))*64 + kk]);
      #pragma unroll
      for (int mf = 0; mf < 4; ++mf)
        #pragma unroll
        for (int nf = 0; nf < 4; ++nf)
          acc[mf][nf] = __builtin_amdgcn_mfma_f32_16x16x32_bf16(af[mf], bfr[nf], acc[mf][nf], 0, 0, 0);
    }
    __syncthreads();
  }

  const int rbase = blockIdx.x*128 + wm*64 + (lane >> 4)*4;
  const int cbase = blockIdx.y*128 + wn*64 + (lane & 15);
  #pragma unroll
  for (int mf = 0; mf < 4; ++mf){
    #pragma unroll
    for (int nf = 0; nf < 4; ++nf){
      const int col = cbase + nf*16;
      if (col < Nout){
        const float bi = bias[col];
        #pragma unroll
        for (int j = 0; j < 4; ++j){
          const int row = rbase + mf*16 + j;
          const float v = acc[mf][nf][j] + bi;
          if (EPI == 0){
            outB[(size_t)row*ldo + col] = f2bf(v);
          } else if (EPI == 1){
            const size_t o = (size_t)row*ldo + col;
            outF[o] = resid[o] + scale[col]*v;
          } else if (EPI == 2){
            const float g = 0.5f*v*(1.0f + erff(v*0.70710678118654752f));
            outB[(size_t)row*ldo + col] = f2bf(g);
          } else {
            const size_t o = (size_t)row*ldo + col;
            outF[o] += scale[col]*v;
          }
        }
      }
    }
  }
}

// ---------------- MFMA attention: one block (4 waves) per (b,h) --------------
// Pad 49 -> 64. QK^T: per wave 4 MFMAs (A/B frags direct from global).
// Softmax in-register on C layout. P -> LDS (XOR (row&7)<<4 swizzle).
// V -> LDS (XOR ((k>>3)&3)<<5 swizzle, pad rows zeroed). PV: 16 MFMAs/wave.
__global__ __launch_bounds__(256)
void attn_mfma_k(const unsigned short* __restrict__ qkv,
                 const float* __restrict__ biasf,   // [8][64][64]
                 unsigned short* __restrict__ ctx)
{
  const int bh = blockIdx.x;
  const int b = bh >> 3, h = bh & 7;
  __shared__ unsigned short Vs[64*128];   // 16 KB, swizzled
  __shared__ unsigned short Ps[64*64];    //  8 KB, swizzled
  const int t = threadIdx.x, lane = t & 63, w = t >> 6;
  const int g = lane >> 4, li = lane & 15;
  const size_t qbase = ((size_t)b*49)*QKVO + (size_t)h*192;

  // ---- stage V (rows >=49 zeroed: P=0 x garbage would be NaN) ----
  for (int c = t; c < 64*16; c += 256){
    const int k = c >> 4, seg = c & 15;
    bf16x8 v = {};
    if (k < 49)
      v = *reinterpret_cast<const bf16x8*>(qkv + qbase + 64 + (size_t)k*QKVO + seg*8);
    const int byte = (k*256 + seg*16) ^ ((((unsigned)k >> 3) & 3) << 5);
    *reinterpret_cast<bf16x8*>((char*)Vs + byte) = v;
  }

  // ---- QK^T: A-frag = Q row (w*16+li), B-frag[nf] = K row (nf*16+li) ----
  const int qrow = w*16 + li;
  bf16x8 afq = {};
  if (qrow < 49)
    afq = *reinterpret_cast<const bf16x8*>(qkv + qbase + (size_t)qrow*QKVO + g*8);
  f32x4 accs[4];
  #pragma unroll
  for (int nf = 0; nf < 4; ++nf){
    const int krow = nf*16 + li;
    bf16x8 bfr = {};
    if (krow < 49)
      bfr = *reinterpret_cast<const bf16x8*>(qkv + qbase + 32 + (size_t)krow*QKVO + g*8);
    f32x4 z = {};
    accs[nf] = __builtin_amdgcn_mfma_f32_16x16x32_bf16(afq, bfr, z, 0, 0, 0);
  }

  // ---- softmax per row (row = w*16 + g*4 + j, 16 lanes/row hold 64 cols) ----
  #pragma unroll
  for (int j = 0; j < 4; ++j){
    const int row = w*16 + g*4 + j;
    float sv[4];
    #pragma unroll
    for (int nf = 0; nf < 4; ++nf)
      sv[nf] = accs[nf][j]*SCALE_ + biasf[h*4096 + row*64 + nf*16 + li];
    float m = fmaxf(fmaxf(sv[0], sv[1]), fmaxf(sv[2], sv[3]));
    #pragma unroll
    for (int o = 8; o; o >>= 1) m = fmaxf(m, __shfl_xor(m, o));
    float e[4], s = 0.f;
    #pragma unroll
    for (int nf = 0; nf < 4; ++nf){ e[nf] = __expf(sv[nf] - m); s += e[nf]; }
    #pragma unroll
    for (int o = 8; o; o >>= 1) s += __shfl_xor(s, o);
    const float inv = 1.f / s;
    #pragma unroll
    for (int nf = 0; nf < 4; ++nf){
      const int byte = (row*128 + (nf*16 + li)*2) ^ ((row & 7) << 4);
      *reinterpret_cast<unsigned short*>((char*)Ps + byte) = f2bf(e[nf]*inv);
    }
  }
  __syncthreads();

  // ---- PV: wave w owns d-cols [w*32, w*32+32) ----
  f32x4 accp[4][2] = {};
  #pragma unroll
  for (int kt = 0; kt < 2; ++kt){
    bf16x8 pa[4];
    #pragma unroll
    for (int mt = 0; mt < 4; ++mt){
      const int q = mt*16 + li;
      const int byte = (q*128 + kt*64 + g*16) ^ ((q & 7) << 4);
      pa[mt] = *reinterpret_cast<const bf16x8*>((char*)Ps + byte);
    }
    #pragma unroll
    for (int nf = 0; nf < 2; ++nf){
      const int d = w*32 + nf*16 + li;
      ushort8 vbu;
      #pragma unroll
      for (int j = 0; j < 8; ++j){
        const int k = kt*32 + g*8 + j;
        const int byte = (k*256 + d*2) ^ ((((unsigned)k >> 3) & 3) << 5);
        vbu[j] = *reinterpret_cast<const unsigned short*>((char*)Vs + byte);
      }
      const bf16x8 vb = __builtin_bit_cast(bf16x8, vbu);
      #pragma unroll
      for (int mt = 0; mt < 4; ++mt)
        accp[mt][nf] = __builtin_amdgcn_mfma_f32_16x16x32_bf16(pa[mt], vb, accp[mt][nf], 0, 0, 0);
    }
  }

  // ---- store ctx[q][w*32+nf*16+li] ----
  const size_t obase = ((size_t)b*49)*1024 + (size_t)h*128;
  #pragma unroll
  for (int mt = 0; mt < 4; ++mt){
    #pragma unroll
    for (int nf = 0; nf < 2; ++nf){
      #pragma unroll
      for (int j = 0; j < 4; ++j){
        const int row = mt*16 + g*4 + j;
        if (row < 49){
          const int col = w*32 + nf*16 + li;
          ctx[obase + (size_t)row*1024 + col] = f2bf(accp[mt][nf][j]);
        }
      }
    }
  }
}

// ---------------------------------------------------------------------------
extern "C" void kernel_launch(void* const* d_in, const int* in_sizes, int n_in,
                              void* d_out, int out_size, void* d_ws, size_t ws_size,
                              hipStream_t stream)
{
  const float* hidden = (const float*)d_in[0];
  const float* ln2w   = (const float*)d_in[1];
  const float* ln2b   = (const float*)d_in[2];
  const float* qkvw   = (const float*)d_in[3];
  const float* qkvb   = (const float*)d_in[4];
  const float* projw  = (const float*)d_in[5];
  const float* projb  = (const float*)d_in[6];
  const float* attb   = (const float*)d_in[7];
  const float* fc1w   = (const float*)d_in[8];
  const float* fc1b   = (const float*)d_in[9];
  const float* fc2w   = (const float*)d_in[10];
  const float* fc2b   = (const float*)d_in[11];
  const float* ls1    = (const float*)d_in[12];
  const float* ls2    = (const float*)d_in[13];
  const int*   aidx   = (const int*)d_in[14];
  float* out = (float*)d_out;

  char* p = (char*)d_ws;
  auto alloc = [&](size_t bytes){ void* r = (void*)p; p += (bytes + 255) & ~(size_t)255; return r; };
  unsigned short* wqkv  = (unsigned short*)alloc((size_t)QKVO*448*2);
  unsigned short* wproj = (unsigned short*)alloc((size_t)512*1024*2);   // 448 padded to 512
  unsigned short* wfc1  = (unsigned short*)alloc((size_t)MLPH*448*2);
  unsigned short* wfc2  = (unsigned short*)alloc((size_t)512*MLPH*2);   // 448 padded to 512
  unsigned short* normb = (unsigned short*)alloc((size_t)NTOK*448*2);
  unsigned short* qkvv  = (unsigned short*)alloc((size_t)NTOK*QKVO*2);
  unsigned short* ctx   = (unsigned short*)alloc((size_t)NTOK*1024*2);
  unsigned short* hid   = (unsigned short*)alloc((size_t)NTOK*MLPH*2);
  float*          biasf = (float*)alloc((size_t)8*64*64*4);

  auto cvt = [&](const float* s, unsigned short* d, int Nout, int K, long total){
    cvt_k<<<(int)((total + 255)/256), 256, 0, stream>>>(s, d, Nout, K, total);
  };
  cvt(qkvw,  wqkv,  QKVO, 448,  (long)QKVO*448);
  cvt(projw, wproj, 448,  1024, (long)512*1024);
  cvt(fc1w,  wfc1,  MLPH, 448,  (long)MLPH*448);
  cvt(fc2w,  wfc2,  448,  MLPH, (long)512*MLPH);

  biasf_k<<<(8*64*64 + 255)/256, 256, 0, stream>>>(attb, aidx, biasf);

  ln_k<<<NTOK, 448, 0, stream>>>(hidden, ln2w, ln2b, normb);

  // QKV: [12544,448] x [1536,448]^T -> bf16 qkv
  gemm_k<0><<<dim3(98,12), 256, 0, stream>>>(normb, wqkv, 448, QKVO, qkvb,
                                             nullptr, nullptr, nullptr, qkvv, QKVO);
  // attention per (b,h), MFMA
  attn_mfma_k<<<B_*H_, 256, 0, stream>>>(qkvv, biasf, ctx);
  // proj: [12544,1024] x [448,1024]^T -> out = hidden + ls1*(..)
  gemm_k<1><<<dim3(98,4), 256, 0, stream>>>(ctx, wproj, 1024, 448, projb,
                                            hidden, ls1, out, nullptr, 448);
  // FC1: [12544,448] x [1792,448]^T -> gelu -> bf16 hid
  gemm_k<2><<<dim3(98,14), 256, 0, stream>>>(normb, wfc1, 448, MLPH, fc1b,
                                             nullptr, nullptr, nullptr, hid, MLPH);
  // FC2: [12544,1792] x [448,1792]^T -> out += ls2*(..)
  gemm_k<3><<<dim3(98,4), 256, 0, stream>>>(hid, wfc2, MLPH, 448, fc2b,
                                            nullptr, ls2, out, nullptr, 448);
}

// Round 3
// 218.770 us; speedup vs baseline: 1.6815x; 1.1658x over previous
//
#include <hip/hip_runtime.h>
#include <hip/hip_bf16.h>
#include <cstdint>

#define B_    256
#define S_    49
#define D_    448
#define H_    8
#define KD_   32
#define ED_   128
#define NTOK  (B_*S_)          // 12544 = 98*128
#define QKVO  1536
#define MLPH  1792
#define SCALE_ 0.17677669529663687f   // 32^-0.5

using bf16x8  = __attribute__((ext_vector_type(8))) __bf16;
using ushort8 = __attribute__((ext_vector_type(8))) unsigned short;
using f32x4   = __attribute__((ext_vector_type(4))) float;

__device__ __forceinline__ unsigned short f2bf(float f){
  uint32_t u = __builtin_bit_cast(uint32_t, f);
  u += 0x7fffu + ((u >> 16) & 1u);     // RNE
  return (unsigned short)(u >> 16);
}
__device__ __forceinline__ float b2f(unsigned short b){
  uint32_t u = ((uint32_t)b) << 16;
  return __builtin_bit_cast(float, u);
}

__device__ __forceinline__ void gload_lds16(const void* g, void* l){
  __builtin_amdgcn_global_load_lds(
      (const __attribute__((address_space(1))) void*)g,
      (__attribute__((address_space(3))) void*)l, 16, 0, 0);
}

// ---------------- weight fp32 -> bf16 (with zero row padding) ----------------
__global__ __launch_bounds__(256)
void cvt_k(const float* __restrict__ src, unsigned short* __restrict__ dst,
           int Nout, int K, long total){
  long i = (long)blockIdx.x * 256 + threadIdx.x;
  if (i >= total) return;
  long row = i / K;
  unsigned short v = 0;
  if (row < Nout) v = f2bf(src[i]);
  dst[i] = v;
}

// ---------------- attention bias table: biasf[h][64][64] ---------------------
__global__ __launch_bounds__(256)
void biasf_k(const float* __restrict__ attb, const int* __restrict__ idxs,
             float* __restrict__ biasf){
  int i = blockIdx.x * 256 + threadIdx.x;
  if (i >= 8*64*64) return;
  int h = i >> 12, r = (i >> 6) & 63, c = i & 63;
  float v;
  if (c >= 49) v = -1e30f;                       // masked key -> softmax weight 0
  else { int q = r < 49 ? r : 48; v = attb[h*49 + idxs[q*49 + c]]; }
  biasf[i] = v;
}

// ---------------- LayerNorm over D=448, one block (7 waves) per token --------
__global__ __launch_bounds__(448)
void ln_k(const float* __restrict__ x, const float* __restrict__ w,
          const float* __restrict__ b, unsigned short* __restrict__ out){
  const int tok = blockIdx.x, t = threadIdx.x;
  const float v = x[(size_t)tok*448 + t];
  float s1 = v, s2 = v*v;
  #pragma unroll
  for (int o = 32; o; o >>= 1){ s1 += __shfl_xor(s1, o); s2 += __shfl_xor(s2, o); }
  __shared__ float a1[7], a2[7];
  const int wid = t >> 6;
  if ((t & 63) == 0){ a1[wid] = s1; a2[wid] = s2; }
  __syncthreads();
  float S1 = 0.f, S2 = 0.f;
  #pragma unroll
  for (int i = 0; i < 7; ++i){ S1 += a1[i]; S2 += a2[i]; }
  const float mu  = S1 * (1.f/448.f);
  const float var = S2 * (1.f/448.f) - mu*mu;
  const float rs  = rsqrtf(var + 1e-12f);
  out[(size_t)tok*448 + t] = f2bf((v - mu)*rs*w[t] + b[t]);
}

// ---------------- bf16 MFMA GEMM: C[M,Nout] = A[M,K] @ W[Nout,K]^T -----------
// BM=128, BN=64, BK=64. 4 waves (2M x 2N -> each wave 64x32).
// Double-buffered LDS, 2-phase schedule: stage(kt+1) overlaps compute(kt),
// ONE barrier per K-tile. Epilogue: acc -> swizzled LDS f32 tile -> coalesced
// 128B-line stores (f32x4 / ushort8).
// EPI: 0 = +bias -> bf16; 1 = out = resid + scale*(v+bias) (f32);
//      2 = gelu(v+bias) -> bf16; 3 = out += scale*(v+bias) (f32 RMW)
template<int EPI>
__global__ __launch_bounds__(256)
void gemm_k(const unsigned short* __restrict__ A,
            const unsigned short* __restrict__ W,
            int K,
            const float* __restrict__ bias,
            const float* __restrict__ resid,
            const float* __restrict__ scale,
            float* __restrict__ outF,
            unsigned short* __restrict__ outB,
            int ldo)
{
  __shared__ char smem[49152];              // A dbuf 2x16KB | B dbuf 2x8KB; epilogue reuses 32KB as f32 tile
  unsigned short* const As0 = (unsigned short*)smem;
  unsigned short* const As1 = As0 + 8192;
  unsigned short* const Bs0 = (unsigned short*)(smem + 32768);
  unsigned short* const Bs1 = Bs0 + 4096;

  const int t = threadIdx.x, lane = t & 63, wid = t >> 6;
  const int wm = wid >> 1, wn = wid & 1;
  const int g = lane >> 4, li = lane & 15;
  const int bx = blockIdx.x, by = blockIdx.y;
  f32x4 acc[4][2] = {};

  const size_t aBase = (size_t)bx * 128 * K;
  const size_t bBase = (size_t)by * 64 * K;
  const int srow = lane >> 3;               // 8 lanes per 64-elem (128B) row
  const int scol = (lane & 7) * 8;
  const int nkt = K >> 6;

  auto stage = [&](unsigned short* As, unsigned short* Bs, int kt){
    const int k0 = kt * 64;
    #pragma unroll
    for (int i = 0; i < 4; ++i){
      const int c = wid*4 + i;              // 16 chunks x 8 rows = 128 A-rows
      gload_lds16(A + aBase + (size_t)(c*8 + srow)*K + (k0 + scol), As + c*512);
    }
    #pragma unroll
    for (int i = 0; i < 2; ++i){
      const int c = wid*2 + i;              // 8 chunks x 8 rows = 64 B-rows
      gload_lds16(W + bBase + (size_t)(c*8 + srow)*K + (k0 + scol), Bs + c*512);
    }
  };

  unsigned short *Asc = As0, *Asn = As1, *Bsc = Bs0, *Bsn = Bs1;
  stage(Asc, Bsc, 0);
  for (int kt = 0; kt < nkt; ++kt){
    __syncthreads();                        // drains vmcnt(0): buf[cur] ready; one barrier/tile
    if (kt + 1 < nkt) stage(Asn, Bsn, kt + 1);   // in flight across the MFMA phase
    #pragma unroll
    for (int ks = 0; ks < 2; ++ks){
      const int kk = ks*32 + g*8;
      bf16x8 af[4], bfr[2];
      #pragma unroll
      for (int mf = 0; mf < 4; ++mf)
        af[mf]  = *reinterpret_cast<const bf16x8*>(&Asc[(wm*64 + mf*16 + li)*64 + kk]);
      #pragma unroll
      for (int nf = 0; nf < 2; ++nf)
        bfr[nf] = *reinterpret_cast<const bf16x8*>(&Bsc[(wn*32 + nf*16 + li)*64 + kk]);
      #pragma unroll
      for (int mf = 0; mf < 4; ++mf)
        #pragma unroll
        for (int nf = 0; nf < 2; ++nf)
          acc[mf][nf] = __builtin_amdgcn_mfma_f32_16x16x32_bf16(af[mf], bfr[nf], acc[mf][nf], 0, 0, 0);
    }
    { unsigned short* tmp = Asc; Asc = Asn; Asn = tmp; }
    { unsigned short* tmp = Bsc; Bsc = Bsn; Bsn = tmp; }
  }
  __syncthreads();                          // all LDS reads done; reuse smem as Cf

  // ---- acc (+bias / gelu) -> swizzled f32 LDS tile [128][64] ----
  // layout byte(row,col) = row*256 + ((col*4) ^ (((row>>2)&1)<<6))  -> ~2-way write conflicts
  #pragma unroll
  for (int mf = 0; mf < 4; ++mf){
    #pragma unroll
    for (int nf = 0; nf < 2; ++nf){
      const int col = wn*32 + nf*16 + li;
      const float bi = bias[by*64 + col];
      #pragma unroll
      for (int j = 0; j < 4; ++j){
        const int row = wm*64 + mf*16 + g*4 + j;
        float v = acc[mf][nf][j] + bi;
        if (EPI == 2) v = 0.5f*v*(1.0f + erff(v*0.70710678118654752f));
        *reinterpret_cast<float*>(smem + row*256 + ((col*4) ^ (((row >> 2) & 1) << 6))) = v;
      }
    }
  }
  __syncthreads();

  if (EPI == 0 || EPI == 2){
    // 8 lanes cover one 64-col bf16 row (128B line) per instruction
    const int l8r = lane >> 3, l8c = lane & 7;
    #pragma unroll
    for (int i = 0; i < 4; ++i){
      const int r = wid*32 + i*8 + l8r;
      const int sw = ((r >> 2) & 1) << 6;
      const f32x4 v0 = *reinterpret_cast<const f32x4*>(smem + r*256 + ((l8c*32)      ^ sw));
      const f32x4 v1 = *reinterpret_cast<const f32x4*>(smem + r*256 + ((l8c*32 + 16) ^ sw));
      ushort8 u;
      #pragma unroll
      for (int k = 0; k < 4; ++k){ u[k] = f2bf(v0[k]); u[4+k] = f2bf(v1[k]); }
      *reinterpret_cast<ushort8*>(outB + (size_t)(bx*128 + r)*ldo + by*64 + l8c*8) = u;
    }
  } else {
    // 16 lanes cover one 64-col f32 row (256B) per instruction
    const int l16r = lane >> 4, l16c = lane & 15;
    #pragma unroll
    for (int i = 0; i < 8; ++i){
      const int r = wid*32 + i*4 + l16r;
      const int sw = ((r >> 2) & 1) << 6;
      const f32x4 v = *reinterpret_cast<const f32x4*>(smem + r*256 + ((l16c*16) ^ sw));
      const size_t o = (size_t)(bx*128 + r)*448 + by*64 + l16c*4;
      const f32x4 sc = *reinterpret_cast<const f32x4*>(scale + by*64 + l16c*4);
      if (EPI == 1){
        const f32x4 rs = *reinterpret_cast<const f32x4*>(resid + o);
        f32x4 w4 = rs + sc*v;
        *reinterpret_cast<f32x4*>(outF + o) = w4;
      } else {
        f32x4 rs = *reinterpret_cast<const f32x4*>(outF + o);
        rs += sc*v;
        *reinterpret_cast<f32x4*>(outF + o) = rs;
      }
    }
  }
}

// ---------------- MFMA attention: one block (4 waves) per (b,h) --------------
__global__ __launch_bounds__(256)
void attn_mfma_k(const unsigned short* __restrict__ qkv,
                 const float* __restrict__ biasf,   // [8][64][64]
                 unsigned short* __restrict__ ctx)
{
  const int bh = blockIdx.x;
  const int b = bh >> 3, h = bh & 7;
  __shared__ unsigned short Vs[64*128];   // 16 KB, swizzled
  __shared__ unsigned short Ps[64*64];    //  8 KB, swizzled
  const int t = threadIdx.x, lane = t & 63, w = t >> 6;
  const int g = lane >> 4, li = lane & 15;
  const size_t qbase = ((size_t)b*49)*QKVO + (size_t)h*192;

  for (int c = t; c < 64*16; c += 256){
    const int k = c >> 4, seg = c & 15;
    bf16x8 v = {};
    if (k < 49)
      v = *reinterpret_cast<const bf16x8*>(qkv + qbase + 64 + (size_t)k*QKVO + seg*8);
    const int byte = (k*256 + seg*16) ^ ((((unsigned)k >> 3) & 3) << 5);
    *reinterpret_cast<bf16x8*>((char*)Vs + byte) = v;
  }

  const int qrow = w*16 + li;
  bf16x8 afq = {};
  if (qrow < 49)
    afq = *reinterpret_cast<const bf16x8*>(qkv + qbase + (size_t)qrow*QKVO + g*8);
  f32x4 accs[4];
  #pragma unroll
  for (int nf = 0; nf < 4; ++nf){
    const int krow = nf*16 + li;
    bf16x8 bfr = {};
    if (krow < 49)
      bfr = *reinterpret_cast<const bf16x8*>(qkv + qbase + 32 + (size_t)krow*QKVO + g*8);
    f32x4 z = {};
    accs[nf] = __builtin_amdgcn_mfma_f32_16x16x32_bf16(afq, bfr, z, 0, 0, 0);
  }

  #pragma unroll
  for (int j = 0; j < 4; ++j){
    const int row = w*16 + g*4 + j;
    float sv[4];
    #pragma unroll
    for (int nf = 0; nf < 4; ++nf)
      sv[nf] = accs[nf][j]*SCALE_ + biasf[h*4096 + row*64 + nf*16 + li];
    float m = fmaxf(fmaxf(sv[0], sv[1]), fmaxf(sv[2], sv[3]));
    #pragma unroll
    for (int o = 8; o; o >>= 1) m = fmaxf(m, __shfl_xor(m, o));
    float e[4], s = 0.f;
    #pragma unroll
    for (int nf = 0; nf < 4; ++nf){ e[nf] = __expf(sv[nf] - m); s += e[nf]; }
    #pragma unroll
    for (int o = 8; o; o >>= 1) s += __shfl_xor(s, o);
    const float inv = 1.f / s;
    #pragma unroll
    for (int nf = 0; nf < 4; ++nf){
      const int byte = (row*128 + (nf*16 + li)*2) ^ ((row & 7) << 4);
      *reinterpret_cast<unsigned short*>((char*)Ps + byte) = f2bf(e[nf]*inv);
    }
  }
  __syncthreads();

  f32x4 accp[4][2] = {};
  #pragma unroll
  for (int kt = 0; kt < 2; ++kt){
    bf16x8 pa[4];
    #pragma unroll
    for (int mt = 0; mt < 4; ++mt){
      const int q = mt*16 + li;
      const int byte = (q*128 + kt*64 + g*16) ^ ((q & 7) << 4);
      pa[mt] = *reinterpret_cast<const bf16x8*>((char*)Ps + byte);
    }
    #pragma unroll
    for (int nf = 0; nf < 2; ++nf){
      const int d = w*32 + nf*16 + li;
      ushort8 vbu;
      #pragma unroll
      for (int j = 0; j < 8; ++j){
        const int k = kt*32 + g*8 + j;
        const int byte = (k*256 + d*2) ^ ((((unsigned)k >> 3) & 3) << 5);
        vbu[j] = *reinterpret_cast<const unsigned short*>((char*)Vs + byte);
      }
      const bf16x8 vb = __builtin_bit_cast(bf16x8, vbu);
      #pragma unroll
      for (int mt = 0; mt < 4; ++mt)
        accp[mt][nf] = __builtin_amdgcn_mfma_f32_16x16x32_bf16(pa[mt], vb, accp[mt][nf], 0, 0, 0);
    }
  }

  const size_t obase = ((size_t)b*49)*1024 + (size_t)h*128;
  #pragma unroll
  for (int mt = 0; mt < 4; ++mt){
    #pragma unroll
    for (int nf = 0; nf < 2; ++nf){
      #pragma unroll
      for (int j = 0; j < 4; ++j){
        const int row = mt*16 + g*4 + j;
        if (row < 49){
          const int col = w*32 + nf*16 + li;
          ctx[obase + (size_t)row*1024 + col] = f2bf(accp[mt][nf][j]);
        }
      }
    }
  }
}

// ---------------------------------------------------------------------------
extern "C" void kernel_launch(void* const* d_in, const int* in_sizes, int n_in,
                              void* d_out, int out_size, void* d_ws, size_t ws_size,
                              hipStream_t stream)
{
  const float* hidden = (const float*)d_in[0];
  const float* ln2w   = (const float*)d_in[1];
  const float* ln2b   = (const float*)d_in[2];
  const float* qkvw   = (const float*)d_in[3];
  const float* qkvb   = (const float*)d_in[4];
  const float* projw  = (const float*)d_in[5];
  const float* projb  = (const float*)d_in[6];
  const float* attb   = (const float*)d_in[7];
  const float* fc1w   = (const float*)d_in[8];
  const float* fc1b   = (const float*)d_in[9];
  const float* fc2w   = (const float*)d_in[10];
  const float* fc2b   = (const float*)d_in[11];
  const float* ls1    = (const float*)d_in[12];
  const float* ls2    = (const float*)d_in[13];
  const int*   aidx   = (const int*)d_in[14];
  float* out = (float*)d_out;

  char* p = (char*)d_ws;
  auto alloc = [&](size_t bytes){ void* r = (void*)p; p += (bytes + 255) & ~(size_t)255; return r; };
  unsigned short* wqkv  = (unsigned short*)alloc((size_t)QKVO*448*2);
  unsigned short* wproj = (unsigned short*)alloc((size_t)512*1024*2);
  unsigned short* wfc1  = (unsigned short*)alloc((size_t)MLPH*448*2);
  unsigned short* wfc2  = (unsigned short*)alloc((size_t)512*MLPH*2);
  unsigned short* normb = (unsigned short*)alloc((size_t)NTOK*448*2);
  unsigned short* qkvv  = (unsigned short*)alloc((size_t)NTOK*QKVO*2);
  unsigned short* ctx   = (unsigned short*)alloc((size_t)NTOK*1024*2);
  unsigned short* hid   = (unsigned short*)alloc((size_t)NTOK*MLPH*2);
  float*          biasf = (float*)alloc((size_t)8*64*64*4);

  auto cvt = [&](const float* s, unsigned short* d, int Nout, int K, long total){
    cvt_k<<<(int)((total + 255)/256), 256, 0, stream>>>(s, d, Nout, K, total);
  };
  cvt(qkvw,  wqkv,  QKVO, 448,  (long)QKVO*448);
  cvt(projw, wproj, 448,  1024, (long)512*1024);
  cvt(fc1w,  wfc1,  MLPH, 448,  (long)MLPH*448);
  cvt(fc2w,  wfc2,  448,  MLPH, (long)512*MLPH);

  biasf_k<<<(8*64*64 + 255)/256, 256, 0, stream>>>(attb, aidx, biasf);

  ln_k<<<NTOK, 448, 0, stream>>>(hidden, ln2w, ln2b, normb);

  // QKV: [12544,448] x [1536,448]^T -> bf16 qkv
  gemm_k<0><<<dim3(98,24), 256, 0, stream>>>(normb, wqkv, 448, qkvb,
                                             nullptr, nullptr, nullptr, qkvv, QKVO);
  // attention per (b,h), MFMA
  attn_mfma_k<<<B_*H_, 256, 0, stream>>>(qkvv, biasf, ctx);
  // proj: [12544,1024] x [448,1024]^T -> out = hidden + ls1*(..)
  gemm_k<1><<<dim3(98,7), 256, 0, stream>>>(ctx, wproj, 1024, projb,
                                            hidden, ls1, out, nullptr, 448);
  // FC1: [12544,448] x [1792,448]^T -> gelu -> bf16 hid
  gemm_k<2><<<dim3(98,28), 256, 0, stream>>>(normb, wfc1, 448, fc1b,
                                             nullptr, nullptr, nullptr, hid, MLPH);
  // FC2: [12544,1792] x [448,1792]^T -> out += ls2*(..)
  gemm_k<3><<<dim3(98,7), 256, 0, stream>>>(hid, wfc2, MLPH, fc2b,
                                            nullptr, ls2, out, nullptr, 448);
}

// Round 4
// 201.233 us; speedup vs baseline: 1.8280x; 1.0871x over previous
//
#include <hip/hip_runtime.h>
#include <hip/hip_bf16.h>
#include <cstdint>

#define B_    256
#define S_    49
#define D_    448
#define H_    8
#define KD_   32
#define ED_   128
#define NTOK  (B_*S_)          // 12544 = 98*128
#define QKVO  1536
#define MLPH  1792
#define SCALE_ 0.17677669529663687f   // 32^-0.5

using bf16x8  = __attribute__((ext_vector_type(8))) __bf16;
using ushort8 = __attribute__((ext_vector_type(8))) unsigned short;
using f32x4   = __attribute__((ext_vector_type(4))) float;

__device__ __forceinline__ unsigned short f2bf(float f){
  uint32_t u = __builtin_bit_cast(uint32_t, f);
  u += 0x7fffu + ((u >> 16) & 1u);     // RNE
  return (unsigned short)(u >> 16);
}
__device__ __forceinline__ float b2f(unsigned short b){
  uint32_t u = ((uint32_t)b) << 16;
  return __builtin_bit_cast(float, u);
}

__device__ __forceinline__ void gload_lds16(const void* g, void* l){
  __builtin_amdgcn_global_load_lds(
      (const __attribute__((address_space(1))) void*)g,
      (__attribute__((address_space(3))) void*)l, 16, 0, 0);
}

// ---------- weight fp32 -> bf16, optional per-row scale, strided dest -------
__global__ __launch_bounds__(256)
void cvt_k(const float* __restrict__ src, unsigned short* __restrict__ dst,
           int K, int ldd, int coloff, const float* __restrict__ scale,
           long total){
  long i = (long)blockIdx.x * 256 + threadIdx.x;
  if (i >= total) return;
  long row = i / K, col = i - row*K;
  float s = scale ? scale[row] : 1.f;
  dst[row*(long)ldd + coloff + col] = f2bf(src[i]*s);
}

// ---------- combined bias: cb = ls1*projb + ls2*fc2b ------------------------
__global__ void cb_k(const float* ls1, const float* pb,
                     const float* ls2, const float* fb, float* cb){
  int i = threadIdx.x;
  if (i < 448) cb[i] = ls1[i]*pb[i] + ls2[i]*fb[i];
}

// ---------- attention bias table: biasf[h][64][64] --------------------------
__global__ __launch_bounds__(256)
void biasf_k(const float* __restrict__ attb, const int* __restrict__ idxs,
             float* __restrict__ biasf){
  int i = blockIdx.x * 256 + threadIdx.x;
  if (i >= 8*64*64) return;
  int h = i >> 12, r = (i >> 6) & 63, c = i & 63;
  float v;
  if (c >= 49) v = -1e30f;                       // masked key -> softmax weight 0
  else { int q = r < 49 ? r : 48; v = attb[h*49 + idxs[q*49 + c]]; }
  biasf[i] = v;
}

// ---------- LayerNorm over D=448, one block (7 waves) per token -------------
__global__ __launch_bounds__(448)
void ln_k(const float* __restrict__ x, const float* __restrict__ w,
          const float* __restrict__ b, unsigned short* __restrict__ out){
  const int tok = blockIdx.x, t = threadIdx.x;
  const float v = x[(size_t)tok*448 + t];
  float s1 = v, s2 = v*v;
  #pragma unroll
  for (int o = 32; o; o >>= 1){ s1 += __shfl_xor(s1, o); s2 += __shfl_xor(s2, o); }
  __shared__ float a1[7], a2[7];
  const int wid = t >> 6;
  if ((t & 63) == 0){ a1[wid] = s1; a2[wid] = s2; }
  __syncthreads();
  float S1 = 0.f, S2 = 0.f;
  #pragma unroll
  for (int i = 0; i < 7; ++i){ S1 += a1[i]; S2 += a2[i]; }
  const float mu  = S1 * (1.f/448.f);
  const float var = S2 * (1.f/448.f) - mu*mu;
  const float rs  = rsqrtf(var + 1e-12f);
  out[(size_t)tok*448 + t] = f2bf((v - mu)*rs*w[t] + b[t]);
}

// ---------- bf16 MFMA GEMM: C[M,*] = A[M,K] @ W[*,K]^T ----------------------
// BM=128, BN in {64,128}, BK=64, 4 waves (2x2). Double-buffered LDS, one
// barrier per K-tile. T2 swizzle via pre-swizzled GLOBAL source col
// (gload_lds dest linear) + XOR'd ds_read addr: byte ^= (row&7)<<4.
// Optional second A segment (fused proj+FC2: K = nkt1*64 from A1, rest A2).
// EPI: 0 = +bias -> bf16; 1 = out = resid + bias + acc (f32);
//      2 = gelu(acc+bias) -> bf16
template<int BN, int EPI>
__global__ __launch_bounds__(256)
void gemm_k(const unsigned short* __restrict__ A1, int lda1, int nkt1,
            const unsigned short* __restrict__ A2, int lda2, int nkt,
            const unsigned short* __restrict__ W, int ldw,
            const float* __restrict__ bias,
            const float* __restrict__ resid,
            float* __restrict__ outF,
            unsigned short* __restrict__ outB, int ldo)
{
  constexpr int NF   = BN/32;                       // B frags per wave per ks
  constexpr int SMEM = (BN==128) ? 65536 : 49152;
  __shared__ char smem[SMEM];
  unsigned short* const As0 = (unsigned short*)smem;        // 16KB
  unsigned short* const As1 = As0 + 8192;                   // 16KB
  unsigned short* const Bs0 = As1 + 8192;                   // BN*128 B
  unsigned short* const Bs1 = Bs0 + BN*64;

  const int t = threadIdx.x, lane = t & 63, wid = t >> 6;
  const int wm = wid >> 1, wn = wid & 1;
  const int g = lane >> 4, li = lane & 15;
  const int bx = blockIdx.x, by = blockIdx.y;
  f32x4 acc[4][NF] = {};

  const int srow  = lane >> 3;                      // row within 8-row chunk
  const int scolw = ((lane & 7) ^ srow) * 8;        // pre-swizzled source col

  auto stage = [&](unsigned short* As, unsigned short* Bs, int kt){
    const unsigned short* Ab; int lda, k0;
    if (kt < nkt1){ Ab = A1; lda = lda1; k0 = kt*64; }
    else          { Ab = A2; lda = lda2; k0 = (kt - nkt1)*64; }
    #pragma unroll
    for (int i = 0; i < 4; ++i){
      const int c = wid*4 + i;                      // 16 chunks x 8 rows = 128
      gload_lds16(Ab + (size_t)(bx*128 + c*8 + srow)*lda + k0 + scolw, As + c*512);
    }
    #pragma unroll
    for (int i = 0; i < BN/32; ++i){
      const int c = wid*(BN/32) + i;                // BN/8 chunks
      gload_lds16(W + (size_t)(by*BN + c*8 + srow)*ldw + kt*64 + scolw, Bs + c*512);
    }
  };

  unsigned short *Asc = As0, *Asn = As1, *Bsc = Bs0, *Bsn = Bs1;
  stage(Asc, Bsc, 0);
  for (int kt = 0; kt < nkt; ++kt){
    __syncthreads();                                // buf[cur] ready (vmcnt drained)
    if (kt + 1 < nkt) stage(Asn, Bsn, kt + 1);      // in flight across MFMA phase
    #pragma unroll
    for (int ks = 0; ks < 2; ++ks){
      const int kk2 = (ks*32 + g*8)*2;              // byte offset in K-slice
      bf16x8 af[4], bfr[NF];
      #pragma unroll
      for (int mf = 0; mf < 4; ++mf){
        const int row = wm*64 + mf*16 + li;
        af[mf] = *reinterpret_cast<const bf16x8*>(
            (char*)Asc + row*128 + (kk2 ^ ((row & 7) << 4)));
      }
      #pragma unroll
      for (int nf = 0; nf < NF; ++nf){
        const int row = wn*(BN/2) + nf*16 + li;
        bfr[nf] = *reinterpret_cast<const bf16x8*>(
            (char*)Bsc + row*128 + (kk2 ^ ((row & 7) << 4)));
      }
      #pragma unroll
      for (int mf = 0; mf < 4; ++mf)
        #pragma unroll
        for (int nf = 0; nf < NF; ++nf)
          acc[mf][nf] = __builtin_amdgcn_mfma_f32_16x16x32_bf16(af[mf], bfr[nf], acc[mf][nf], 0, 0, 0);
    }
    { unsigned short* tmp = Asc; Asc = Asn; Asn = tmp; }
    { unsigned short* tmp = Bsc; Bsc = Bsn; Bsn = tmp; }
  }
  __syncthreads();                                  // reuse smem as f32 tile

  // ---- acc (+bias / gelu) -> swizzled f32 LDS tile [128][BN] ----
  auto swz = [&](int r){ return (BN==128) ? ((r>>2)&3)<<6 : ((r>>2)&1)<<6; };
  #pragma unroll
  for (int mf = 0; mf < 4; ++mf){
    #pragma unroll
    for (int nf = 0; nf < NF; ++nf){
      const int col = wn*(BN/2) + nf*16 + li;
      const float bi = bias[by*BN + col];
      #pragma unroll
      for (int j = 0; j < 4; ++j){
        const int row = wm*64 + mf*16 + g*4 + j;
        float v = acc[mf][nf][j] + bi;
        if (EPI == 2) v = 0.5f*v*(1.0f + erff(v*0.70710678118654752f));
        *reinterpret_cast<float*>(smem + row*(BN*4) + ((col*4) ^ swz(row))) = v;
      }
    }
  }
  __syncthreads();

  if (EPI == 0 || EPI == 2){
    constexpr int LPR = BN/8;                       // lanes per output row
    constexpr int RPI = 64/LPR;                     // rows per instruction
    const int lr = lane / LPR, lc = lane % LPR;
    #pragma unroll
    for (int it = 0; it < 32/RPI; ++it){
      const int r = wid*32 + it*RPI + lr;
      const int sw = swz(r);
      const f32x4 v0 = *reinterpret_cast<const f32x4*>(smem + r*(BN*4) + ((lc*32)      ^ sw));
      const f32x4 v1 = *reinterpret_cast<const f32x4*>(smem + r*(BN*4) + ((lc*32 + 16) ^ sw));
      ushort8 u;
      #pragma unroll
      for (int k = 0; k < 4; ++k){ u[k] = f2bf(v0[k]); u[4+k] = f2bf(v1[k]); }
      *reinterpret_cast<ushort8*>(outB + (size_t)(bx*128 + r)*ldo + by*BN + lc*8) = u;
    }
  } else {
    const int l16r = lane >> 4, l16c = lane & 15;
    #pragma unroll
    for (int i = 0; i < 8; ++i){
      const int r = wid*32 + i*4 + l16r;
      const f32x4 v = *reinterpret_cast<const f32x4*>(smem + r*256 + ((l16c*16) ^ swz(r)));
      const size_t o = (size_t)(bx*128 + r)*448 + by*64 + l16c*4;
      const f32x4 rs = *reinterpret_cast<const f32x4*>(resid + o);
      *reinterpret_cast<f32x4*>(outF + o) = rs + v;
    }
  }
}

// ---------- MFMA attention: one block (4 waves) per (b,h) -------------------
__global__ __launch_bounds__(256)
void attn_mfma_k(const unsigned short* __restrict__ qkv,
                 const float* __restrict__ biasf,   // [8][64][64]
                 unsigned short* __restrict__ ctx)
{
  const int bh = blockIdx.x;
  const int b = bh >> 3, h = bh & 7;
  __shared__ unsigned short Vs[64*128];   // 16 KB, swizzled
  __shared__ unsigned short Ps[64*64];    //  8 KB, swizzled
  const int t = threadIdx.x, lane = t & 63, w = t >> 6;
  const int g = lane >> 4, li = lane & 15;
  const size_t qbase = ((size_t)b*49)*QKVO + (size_t)h*192;

  for (int c = t; c < 64*16; c += 256){
    const int k = c >> 4, seg = c & 15;
    bf16x8 v = {};
    if (k < 49)
      v = *reinterpret_cast<const bf16x8*>(qkv + qbase + 64 + (size_t)k*QKVO + seg*8);
    const int byte = (k*256 + seg*16) ^ ((((unsigned)k >> 3) & 3) << 5);
    *reinterpret_cast<bf16x8*>((char*)Vs + byte) = v;
  }

  const int qrow = w*16 + li;
  bf16x8 afq = {};
  if (qrow < 49)
    afq = *reinterpret_cast<const bf16x8*>(qkv + qbase + (size_t)qrow*QKVO + g*8);
  f32x4 accs[4];
  #pragma unroll
  for (int nf = 0; nf < 4; ++nf){
    const int krow = nf*16 + li;
    bf16x8 bfr = {};
    if (krow < 49)
      bfr = *reinterpret_cast<const bf16x8*>(qkv + qbase + 32 + (size_t)krow*QKVO + g*8);
    f32x4 z = {};
    accs[nf] = __builtin_amdgcn_mfma_f32_16x16x32_bf16(afq, bfr, z, 0, 0, 0);
  }

  #pragma unroll
  for (int j = 0; j < 4; ++j){
    const int row = w*16 + g*4 + j;
    float sv[4];
    #pragma unroll
    for (int nf = 0; nf < 4; ++nf)
      sv[nf] = accs[nf][j]*SCALE_ + biasf[h*4096 + row*64 + nf*16 + li];
    float m = fmaxf(fmaxf(sv[0], sv[1]), fmaxf(sv[2], sv[3]));
    #pragma unroll
    for (int o = 8; o; o >>= 1) m = fmaxf(m, __shfl_xor(m, o));
    float e[4], s = 0.f;
    #pragma unroll
    for (int nf = 0; nf < 4; ++nf){ e[nf] = __expf(sv[nf] - m); s += e[nf]; }
    #pragma unroll
    for (int o = 8; o; o >>= 1) s += __shfl_xor(s, o);
    const float inv = 1.f / s;
    #pragma unroll
    for (int nf = 0; nf < 4; ++nf){
      const int byte = (row*128 + (nf*16 + li)*2) ^ ((row & 7) << 4);
      *reinterpret_cast<unsigned short*>((char*)Ps + byte) = f2bf(e[nf]*inv);
    }
  }
  __syncthreads();

  f32x4 accp[4][2] = {};
  #pragma unroll
  for (int kt = 0; kt < 2; ++kt){
    bf16x8 pa[4];
    #pragma unroll
    for (int mt = 0; mt < 4; ++mt){
      const int q = mt*16 + li;
      const int byte = (q*128 + kt*64 + g*16) ^ ((q & 7) << 4);
      pa[mt] = *reinterpret_cast<const bf16x8*>((char*)Ps + byte);
    }
    #pragma unroll
    for (int nf = 0; nf < 2; ++nf){
      const int d = w*32 + nf*16 + li;
      ushort8 vbu;
      #pragma unroll
      for (int j = 0; j < 8; ++j){
        const int k = kt*32 + g*8 + j;
        const int byte = (k*256 + d*2) ^ ((((unsigned)k >> 3) & 3) << 5);
        vbu[j] = *reinterpret_cast<const unsigned short*>((char*)Vs + byte);
      }
      const bf16x8 vb = __builtin_bit_cast(bf16x8, vbu);
      #pragma unroll
      for (int mt = 0; mt < 4; ++mt)
        accp[mt][nf] = __builtin_amdgcn_mfma_f32_16x16x32_bf16(pa[mt], vb, accp[mt][nf], 0, 0, 0);
    }
  }

  const size_t obase = ((size_t)b*49)*1024 + (size_t)h*128;
  #pragma unroll
  for (int mt = 0; mt < 4; ++mt){
    #pragma unroll
    for (int nf = 0; nf < 2; ++nf){
      #pragma unroll
      for (int j = 0; j < 4; ++j){
        const int row = mt*16 + g*4 + j;
        if (row < 49){
          const int col = w*32 + nf*16 + li;
          ctx[obase + (size_t)row*1024 + col] = f2bf(accp[mt][nf][j]);
        }
      }
    }
  }
}

// ---------------------------------------------------------------------------
extern "C" void kernel_launch(void* const* d_in, const int* in_sizes, int n_in,
                              void* d_out, int out_size, void* d_ws, size_t ws_size,
                              hipStream_t stream)
{
  const float* hidden = (const float*)d_in[0];
  const float* ln2w   = (const float*)d_in[1];
  const float* ln2b   = (const float*)d_in[2];
  const float* qkvw   = (const float*)d_in[3];
  const float* qkvb   = (const float*)d_in[4];
  const float* projw  = (const float*)d_in[5];
  const float* projb  = (const float*)d_in[6];
  const float* attb   = (const float*)d_in[7];
  const float* fc1w   = (const float*)d_in[8];
  const float* fc1b   = (const float*)d_in[9];
  const float* fc2w   = (const float*)d_in[10];
  const float* fc2b   = (const float*)d_in[11];
  const float* ls1    = (const float*)d_in[12];
  const float* ls2    = (const float*)d_in[13];
  const int*   aidx   = (const int*)d_in[14];
  float* out = (float*)d_out;

  char* p = (char*)d_ws;
  auto alloc = [&](size_t bytes){ void* r = (void*)p; p += (bytes + 255) & ~(size_t)255; return r; };
  unsigned short* wqkv   = (unsigned short*)alloc((size_t)QKVO*448*2);
  unsigned short* wfc1   = (unsigned short*)alloc((size_t)MLPH*448*2);
  unsigned short* wfused = (unsigned short*)alloc((size_t)448*2816*2);  // [448][1024 proj*ls1 | 1792 fc2*ls2]
  unsigned short* normb  = (unsigned short*)alloc((size_t)NTOK*448*2);
  unsigned short* qkvv   = (unsigned short*)alloc((size_t)NTOK*QKVO*2);
  unsigned short* ctx    = (unsigned short*)alloc((size_t)NTOK*1024*2);
  unsigned short* hid    = (unsigned short*)alloc((size_t)NTOK*MLPH*2);
  float*          biasf  = (float*)alloc((size_t)8*64*64*4);
  float*          cbv    = (float*)alloc((size_t)448*4);

  auto cvt = [&](const float* s, unsigned short* d, int rows, int K, int ldd,
                 int coloff, const float* scale){
    long total = (long)rows*K;
    cvt_k<<<(int)((total + 255)/256), 256, 0, stream>>>(s, d, K, ldd, coloff, scale, total);
  };
  cvt(qkvw,  wqkv,   QKVO, 448,  448,  0,    nullptr);
  cvt(fc1w,  wfc1,   MLPH, 448,  448,  0,    nullptr);
  cvt(projw, wfused, 448,  1024, 2816, 0,    ls1);
  cvt(fc2w,  wfused, 448,  1792, 2816, 1024, ls2);
  cb_k<<<1, 448, 0, stream>>>(ls1, projb, ls2, fc2b, cbv);
  biasf_k<<<(8*64*64 + 255)/256, 256, 0, stream>>>(attb, aidx, biasf);

  ln_k<<<NTOK, 448, 0, stream>>>(hidden, ln2w, ln2b, normb);

  // QKV: [12544,448] x [1536,448]^T -> bf16 qkv
  gemm_k<128,0><<<dim3(98,12), 256, 0, stream>>>(normb, 448, 7, nullptr, 0, 7,
                                                 wqkv, 448, qkvb,
                                                 nullptr, nullptr, qkvv, QKVO);
  // attention per (b,h), MFMA
  attn_mfma_k<<<B_*H_, 256, 0, stream>>>(qkvv, biasf, ctx);
  // FC1: [12544,448] x [1792,448]^T -> gelu -> bf16 hid
  gemm_k<128,2><<<dim3(98,14), 256, 0, stream>>>(normb, 448, 7, nullptr, 0, 7,
                                                 wfc1, 448, fc1b,
                                                 nullptr, nullptr, hid, MLPH);
  // fused proj+FC2: [ctx|hid] x wfused^T, out = hidden + cb + acc
  gemm_k<64,1><<<dim3(98,7), 256, 0, stream>>>(ctx, 1024, 16, hid, MLPH, 44,
                                               wfused, 2816, cbv,
                                               hidden, out, nullptr, 448);
}

// Round 5
// 174.935 us; speedup vs baseline: 2.1028x; 1.1503x over previous
//
#include <hip/hip_runtime.h>
#include <hip/hip_bf16.h>
#include <cstdint>

#define B_    256
#define S_    49
#define D_    448
#define H_    8
#define KD_   32
#define ED_   128
#define NTOK  (B_*S_)          // 12544 = 98*128
#define QKVO  1536
#define MLPH  1792
#define SCALE_ 0.17677669529663687f   // 32^-0.5

using bf16x8  = __attribute__((ext_vector_type(8))) __bf16;
using ushort8 = __attribute__((ext_vector_type(8))) unsigned short;
using f32x4   = __attribute__((ext_vector_type(4))) float;

__device__ __forceinline__ unsigned short f2bf(float f){
  uint32_t u = __builtin_bit_cast(uint32_t, f);
  u += 0x7fffu + ((u >> 16) & 1u);     // RNE
  return (unsigned short)(u >> 16);
}
__device__ __forceinline__ float b2f(unsigned short b){
  uint32_t u = ((uint32_t)b) << 16;
  return __builtin_bit_cast(float, u);
}

__device__ __forceinline__ void gload_lds16(const void* g, void* l){
  __builtin_amdgcn_global_load_lds(
      (const __attribute__((address_space(1))) void*)g,
      (__attribute__((address_space(3))) void*)l, 16, 0, 0);
}

// ---------- prep: all weight cvt + bias tables in ONE kernel ----------------
// seg0 qkvw->wcat[0:1536), seg1 fc1w->wcat[1536:3328)
// seg2 projw*ls1 -> wfused[r][0:1024), seg3 fc2w*ls2 -> wfused[r][1024:2816)
// seg4 zero wfused rows 448..511, seg5 cbig, seg6 cbv, seg7 biasf
#define P_S0 688128L
#define P_S1 1490944L
#define P_S2 1949696L
#define P_S3 2752512L
#define P_S4 2932736L
#define P_S5 2936064L
#define P_S6 2936576L
#define P_S7 2969344L
__global__ __launch_bounds__(256)
void prep_k(const float* __restrict__ qkvw, const float* __restrict__ fc1w,
            const float* __restrict__ projw, const float* __restrict__ fc2w,
            const float* __restrict__ ls1, const float* __restrict__ ls2,
            const float* __restrict__ qkvb, const float* __restrict__ fc1b,
            const float* __restrict__ projb, const float* __restrict__ fc2b,
            const float* __restrict__ attb, const int* __restrict__ idxs,
            unsigned short* __restrict__ wcat, unsigned short* __restrict__ wfused,
            float* __restrict__ cbig, float* __restrict__ cbv,
            float* __restrict__ biasf){
  const long i = (long)blockIdx.x * 256 + threadIdx.x;
  if (i < P_S0){
    wcat[i] = f2bf(qkvw[i]);
  } else if (i < P_S1){
    long j = i - P_S0;
    wcat[i] = f2bf(fc1w[j]);
  } else if (i < P_S2){
    long j = i - P_S1;
    long r = j / 1024, c = j - r*1024;
    wfused[r*2816 + c] = f2bf(projw[j]*ls1[r]);
  } else if (i < P_S3){
    long j = i - P_S2;
    long r = j / 1792, c = j - r*1792;
    wfused[r*2816 + 1024 + c] = f2bf(fc2w[j]*ls2[r]);
  } else if (i < P_S4){
    long j = i - P_S3;
    wfused[448L*2816 + j] = 0;
  } else if (i < P_S5){
    long j = i - P_S4;
    cbig[j] = (j < 1536) ? qkvb[j] : fc1b[j - 1536];
  } else if (i < P_S6){
    long j = i - P_S5;
    cbv[j] = (j < 448) ? ls1[j]*projb[j] + ls2[j]*fc2b[j] : 0.f;
  } else if (i < P_S7){
    long j = i - P_S6;
    int h = (int)(j >> 12), r = (int)((j >> 6) & 63), c = (int)(j & 63);
    float v;
    if (c >= 49) v = -1e30f;
    else { int q = r < 49 ? r : 48; v = attb[h*49 + idxs[q*49 + c]]; }
    biasf[j] = v;
  }
}

// ---------- LayerNorm over D=448, one block (7 waves) per token -------------
__global__ __launch_bounds__(448)
void ln_k(const float* __restrict__ x, const float* __restrict__ w,
          const float* __restrict__ b, unsigned short* __restrict__ out){
  const int tok = blockIdx.x, t = threadIdx.x;
  const float v = x[(size_t)tok*448 + t];
  float s1 = v, s2 = v*v;
  #pragma unroll
  for (int o = 32; o; o >>= 1){ s1 += __shfl_xor(s1, o); s2 += __shfl_xor(s2, o); }
  __shared__ float a1[7], a2[7];
  const int wid = t >> 6;
  if ((t & 63) == 0){ a1[wid] = s1; a2[wid] = s2; }
  __syncthreads();
  float S1 = 0.f, S2 = 0.f;
  #pragma unroll
  for (int i = 0; i < 7; ++i){ S1 += a1[i]; S2 += a2[i]; }
  const float mu  = S1 * (1.f/448.f);
  const float var = S2 * (1.f/448.f) - mu*mu;
  const float rs  = rsqrtf(var + 1e-12f);
  out[(size_t)tok*448 + t] = f2bf((v - mu)*rs*w[t] + b[t]);
}

// ---------- bf16 MFMA GEMM: BM=128, BN=128, BK=64, 4 waves (2x2, 64x64) -----
// Double-buffered LDS (64 KB), one barrier per K-tile, T2 swizzle via
// pre-swizzled global source col + XOR'd ds_read addr (byte ^= (row&7)<<4).
// Optional second A segment (fused proj+FC2). Epilogue via swizzled f32 LDS.
// EPI=4: dual bf16 dest, gelu for by>=splitBy (QKV | FC1 combined)
// EPI=1: out = resid + bias + acc (f32), cols masked to <448
template<int EPI>
__global__ __launch_bounds__(256)
void gemm_k(const unsigned short* __restrict__ A1, int lda1, int nkt1,
            const unsigned short* __restrict__ A2, int lda2, int nkt,
            const unsigned short* __restrict__ W, int ldw,
            const float* __restrict__ bias,
            const float* __restrict__ resid, float* __restrict__ outF,
            unsigned short* __restrict__ outB1, int ldo1,
            unsigned short* __restrict__ outB2, int ldo2, int splitBy)
{
  __shared__ char smem[65536];
  unsigned short* const As0 = (unsigned short*)smem;        // 16 KB
  unsigned short* const As1 = As0 + 8192;
  unsigned short* const Bs0 = As1 + 8192;                   // 16 KB
  unsigned short* const Bs1 = Bs0 + 8192;

  const int t = threadIdx.x, lane = t & 63, wid = t >> 6;
  const int wm = wid >> 1, wn = wid & 1;
  const int g = lane >> 4, li = lane & 15;
  const int bx = blockIdx.x, by = blockIdx.y;
  f32x4 acc[4][4] = {};

  const int srow  = lane >> 3;                      // row within 8-row chunk
  const int scolw = ((lane & 7) ^ srow) * 8;        // pre-swizzled source col

  auto stage = [&](unsigned short* As, unsigned short* Bs, int kt){
    const unsigned short* Ab; int lda, k0;
    if (kt < nkt1){ Ab = A1; lda = lda1; k0 = kt*64; }
    else          { Ab = A2; lda = lda2; k0 = (kt - nkt1)*64; }
    #pragma unroll
    for (int i = 0; i < 4; ++i){
      const int c = wid*4 + i;                      // 16 chunks x 8 rows = 128
      gload_lds16(Ab + (size_t)(bx*128 + c*8 + srow)*lda + k0 + scolw, As + c*512);
    }
    #pragma unroll
    for (int i = 0; i < 4; ++i){
      const int c = wid*4 + i;
      gload_lds16(W + (size_t)(by*128 + c*8 + srow)*ldw + kt*64 + scolw, Bs + c*512);
    }
  };

  unsigned short *Asc = As0, *Asn = As1, *Bsc = Bs0, *Bsn = Bs1;
  stage(Asc, Bsc, 0);
  for (int kt = 0; kt < nkt; ++kt){
    __syncthreads();                                // buf[cur] ready (vmcnt drained)
    if (kt + 1 < nkt) stage(Asn, Bsn, kt + 1);      // in flight across MFMA phase
    #pragma unroll
    for (int ks = 0; ks < 2; ++ks){
      const int kk2 = (ks*32 + g*8)*2;              // byte offset in K-slice
      bf16x8 af[4], bfr[4];
      #pragma unroll
      for (int mf = 0; mf < 4; ++mf){
        const int row = wm*64 + mf*16 + li;
        af[mf] = *reinterpret_cast<const bf16x8*>(
            (char*)Asc + row*128 + (kk2 ^ ((row & 7) << 4)));
      }
      #pragma unroll
      for (int nf = 0; nf < 4; ++nf){
        const int row = wn*64 + nf*16 + li;
        bfr[nf] = *reinterpret_cast<const bf16x8*>(
            (char*)Bsc + row*128 + (kk2 ^ ((row & 7) << 4)));
      }
      #pragma unroll
      for (int mf = 0; mf < 4; ++mf)
        #pragma unroll
        for (int nf = 0; nf < 4; ++nf)
          acc[mf][nf] = __builtin_amdgcn_mfma_f32_16x16x32_bf16(af[mf], bfr[nf], acc[mf][nf], 0, 0, 0);
    }
    { unsigned short* tmp = Asc; Asc = Asn; Asn = tmp; }
    { unsigned short* tmp = Bsc; Bsc = Bsn; Bsn = tmp; }
  }
  __syncthreads();                                  // reuse smem as f32 tile [128][128]

  const bool dogelu = (EPI == 4) && (by >= splitBy);
  #pragma unroll
  for (int mf = 0; mf < 4; ++mf){
    #pragma unroll
    for (int nf = 0; nf < 4; ++nf){
      const int col = wn*64 + nf*16 + li;
      const float bi = bias[by*128 + col];
      #pragma unroll
      for (int j = 0; j < 4; ++j){
        const int row = wm*64 + mf*16 + g*4 + j;
        float v = acc[mf][nf][j] + bi;
        if (dogelu) v = 0.5f*v*(1.0f + erff(v*0.70710678118654752f));
        *reinterpret_cast<float*>(smem + row*512 + ((col*4) ^ (((row >> 2) & 3) << 6))) = v;
      }
    }
  }
  __syncthreads();

  const int lr = lane >> 4, lc = lane & 15;
  if (EPI == 4){
    // 16 lanes x ushort8 cover one 128-col bf16 row per instruction
    #pragma unroll
    for (int it = 0; it < 8; ++it){
      const int r = wid*32 + it*4 + lr;
      const int sw = ((r >> 2) & 3) << 6;
      const f32x4 v0 = *reinterpret_cast<const f32x4*>(smem + r*512 + ((lc*32)      ^ sw));
      const f32x4 v1 = *reinterpret_cast<const f32x4*>(smem + r*512 + ((lc*32 + 16) ^ sw));
      ushort8 u;
      #pragma unroll
      for (int k = 0; k < 4; ++k){ u[k] = f2bf(v0[k]); u[4+k] = f2bf(v1[k]); }
      const int grow = bx*128 + r;
      if (by < splitBy)
        *reinterpret_cast<ushort8*>(outB1 + (size_t)grow*ldo1 + by*128 + lc*8) = u;
      else
        *reinterpret_cast<ushort8*>(outB2 + (size_t)grow*ldo2 + by*128 - splitBy*128 + lc*8) = u;
    }
  } else {
    #pragma unroll
    for (int i = 0; i < 8; ++i){
      const int r = wid*32 + i*4 + lr;
      const int sw = ((r >> 2) & 3) << 6;
      #pragma unroll
      for (int half = 0; half < 2; ++half){
        const int colb = half*64 + lc*4;
        const int gcol = by*128 + colb;
        if (gcol < 448){
          const f32x4 v = *reinterpret_cast<const f32x4*>(smem + r*512 + ((colb*4) ^ sw));
          const size_t o = (size_t)(bx*128 + r)*448 + gcol;
          const f32x4 rs = *reinterpret_cast<const f32x4*>(resid + o);
          *reinterpret_cast<f32x4*>(outF + o) = rs + v;
        }
      }
    }
  }
}

// ---------- MFMA attention: one block (4 waves) per (b,h) -------------------
__global__ __launch_bounds__(256)
void attn_mfma_k(const unsigned short* __restrict__ qkv,
                 const float* __restrict__ biasf,   // [8][64][64]
                 unsigned short* __restrict__ ctx)
{
  const int bh = blockIdx.x;
  const int b = bh >> 3, h = bh & 7;
  __shared__ unsigned short Vs[64*128];   // 16 KB, swizzled
  __shared__ unsigned short Ps[64*64];    //  8 KB, swizzled
  const int t = threadIdx.x, lane = t & 63, w = t >> 6;
  const int g = lane >> 4, li = lane & 15;
  const size_t qbase = ((size_t)b*49)*QKVO + (size_t)h*192;

  for (int c = t; c < 64*16; c += 256){
    const int k = c >> 4, seg = c & 15;
    bf16x8 v = {};
    if (k < 49)
      v = *reinterpret_cast<const bf16x8*>(qkv + qbase + 64 + (size_t)k*QKVO + seg*8);
    const int byte = (k*256 + seg*16) ^ ((((unsigned)k >> 3) & 3) << 5);
    *reinterpret_cast<bf16x8*>((char*)Vs + byte) = v;
  }

  const int qrow = w*16 + li;
  bf16x8 afq = {};
  if (qrow < 49)
    afq = *reinterpret_cast<const bf16x8*>(qkv + qbase + (size_t)qrow*QKVO + g*8);
  f32x4 accs[4];
  #pragma unroll
  for (int nf = 0; nf < 4; ++nf){
    const int krow = nf*16 + li;
    bf16x8 bfr = {};
    if (krow < 49)
      bfr = *reinterpret_cast<const bf16x8*>(qkv + qbase + 32 + (size_t)krow*QKVO + g*8);
    f32x4 z = {};
    accs[nf] = __builtin_amdgcn_mfma_f32_16x16x32_bf16(afq, bfr, z, 0, 0, 0);
  }

  #pragma unroll
  for (int j = 0; j < 4; ++j){
    const int row = w*16 + g*4 + j;
    float sv[4];
    #pragma unroll
    for (int nf = 0; nf < 4; ++nf)
      sv[nf] = accs[nf][j]*SCALE_ + biasf[h*4096 + row*64 + nf*16 + li];
    float m = fmaxf(fmaxf(sv[0], sv[1]), fmaxf(sv[2], sv[3]));
    #pragma unroll
    for (int o = 8; o; o >>= 1) m = fmaxf(m, __shfl_xor(m, o));
    float e[4], s = 0.f;
    #pragma unroll
    for (int nf = 0; nf < 4; ++nf){ e[nf] = __expf(sv[nf] - m); s += e[nf]; }
    #pragma unroll
    for (int o = 8; o; o >>= 1) s += __shfl_xor(s, o);
    const float inv = 1.f / s;
    #pragma unroll
    for (int nf = 0; nf < 4; ++nf){
      const int byte = (row*128 + (nf*16 + li)*2) ^ ((row & 7) << 4);
      *reinterpret_cast<unsigned short*>((char*)Ps + byte) = f2bf(e[nf]*inv);
    }
  }
  __syncthreads();

  f32x4 accp[4][2] = {};
  #pragma unroll
  for (int kt = 0; kt < 2; ++kt){
    bf16x8 pa[4];
    #pragma unroll
    for (int mt = 0; mt < 4; ++mt){
      const int q = mt*16 + li;
      const int byte = (q*128 + kt*64 + g*16) ^ ((q & 7) << 4);
      pa[mt] = *reinterpret_cast<const bf16x8*>((char*)Ps + byte);
    }
    #pragma unroll
    for (int nf = 0; nf < 2; ++nf){
      const int d = w*32 + nf*16 + li;
      ushort8 vbu;
      #pragma unroll
      for (int j = 0; j < 8; ++j){
        const int k = kt*32 + g*8 + j;
        const int byte = (k*256 + d*2) ^ ((((unsigned)k >> 3) & 3) << 5);
        vbu[j] = *reinterpret_cast<const unsigned short*>((char*)Vs + byte);
      }
      const bf16x8 vb = __builtin_bit_cast(bf16x8, vbu);
      #pragma unroll
      for (int mt = 0; mt < 4; ++mt)
        accp[mt][nf] = __builtin_amdgcn_mfma_f32_16x16x32_bf16(pa[mt], vb, accp[mt][nf], 0, 0, 0);
    }
  }

  const size_t obase = ((size_t)b*49)*1024 + (size_t)h*128;
  #pragma unroll
  for (int mt = 0; mt < 4; ++mt){
    #pragma unroll
    for (int nf = 0; nf < 2; ++nf){
      #pragma unroll
      for (int j = 0; j < 4; ++j){
        const int row = mt*16 + g*4 + j;
        if (row < 49){
          const int col = w*32 + nf*16 + li;
          ctx[obase + (size_t)row*1024 + col] = f2bf(accp[mt][nf][j]);
        }
      }
    }
  }
}

// ---------------------------------------------------------------------------
extern "C" void kernel_launch(void* const* d_in, const int* in_sizes, int n_in,
                              void* d_out, int out_size, void* d_ws, size_t ws_size,
                              hipStream_t stream)
{
  const float* hidden = (const float*)d_in[0];
  const float* ln2w   = (const float*)d_in[1];
  const float* ln2b   = (const float*)d_in[2];
  const float* qkvw   = (const float*)d_in[3];
  const float* qkvb   = (const float*)d_in[4];
  const float* projw  = (const float*)d_in[5];
  const float* projb  = (const float*)d_in[6];
  const float* attb   = (const float*)d_in[7];
  const float* fc1w   = (const float*)d_in[8];
  const float* fc1b   = (const float*)d_in[9];
  const float* fc2w   = (const float*)d_in[10];
  const float* fc2b   = (const float*)d_in[11];
  const float* ls1    = (const float*)d_in[12];
  const float* ls2    = (const float*)d_in[13];
  const int*   aidx   = (const int*)d_in[14];
  float* out = (float*)d_out;

  char* p = (char*)d_ws;
  auto alloc = [&](size_t bytes){ void* r = (void*)p; p += (bytes + 255) & ~(size_t)255; return r; };
  unsigned short* wcat   = (unsigned short*)alloc((size_t)3328*448*2);  // [qkv;fc1]
  unsigned short* wfused = (unsigned short*)alloc((size_t)512*2816*2);  // [512][proj*ls1|fc2*ls2]
  unsigned short* normb  = (unsigned short*)alloc((size_t)NTOK*448*2);
  unsigned short* qkvv   = (unsigned short*)alloc((size_t)NTOK*QKVO*2);
  unsigned short* ctx    = (unsigned short*)alloc((size_t)NTOK*1024*2);
  unsigned short* hid    = (unsigned short*)alloc((size_t)NTOK*MLPH*2);
  float*          biasf  = (float*)alloc((size_t)8*64*64*4);
  float*          cbig   = (float*)alloc((size_t)3328*4);
  float*          cbv    = (float*)alloc((size_t)512*4);

  prep_k<<<(int)(P_S7/256), 256, 0, stream>>>(qkvw, fc1w, projw, fc2w, ls1, ls2,
                                              qkvb, fc1b, projb, fc2b, attb, aidx,
                                              wcat, wfused, cbig, cbv, biasf);
  ln_k<<<NTOK, 448, 0, stream>>>(hidden, ln2w, ln2b, normb);

  // QKV+FC1: [12544,448] x [3328,448]^T; by<12 -> qkvv, else gelu -> hid
  gemm_k<4><<<dim3(98,26), 256, 0, stream>>>(normb, 448, 7, nullptr, 448, 7,
                                             wcat, 448, cbig,
                                             nullptr, nullptr,
                                             qkvv, QKVO, hid, MLPH, 12);
  // attention per (b,h), MFMA
  attn_mfma_k<<<B_*H_, 256, 0, stream>>>(qkvv, biasf, ctx);
  // fused proj+FC2: [ctx|hid] x wfused^T (N padded to 512), out = hidden + cb + acc
  gemm_k<1><<<dim3(98,4), 256, 0, stream>>>(ctx, 1024, 16, hid, MLPH, 44,
                                            wfused, 2816, cbv,
                                            hidden, out,
                                            nullptr, 0, nullptr, 0, 999);
}